// Round 1
// baseline (131.673 us; speedup 1.0000x reference)
//
#include <hip/hip_runtime.h>
#include <math.h>

// Problem constants (reference: N=256, S=1, H=W of stimulus = 144x256, retina 144x256)
#define NB    256
#define IMG_H 144
#define IMG_W 256
#define HR    144
#define WR    256
#define FDIM  16
#define DDIM  128

#define FOV_HALF_RAD 0.6544984694978736f   // 0.5 * 75deg in rad
#define GELU_GAMMA   1.7015043497085571f
#define OUT_OF_RANGE 10.0f

// jax.nn.gelu default is approximate=True (tanh form)
__device__ __forceinline__ float gelu_gamma(float x) {
    const float k0 = 0.7978845608028654f;  // sqrt(2/pi)
    const float k1 = 0.044715f;
    float t = tanhf(k0 * (x + k1 * x * x * x));
    return 0.5f * x * (1.0f + t) * GELU_GAMMA;
}

// One block per batch element; 128 threads = hidden dim.
// Writes R[n] (9 floats, row-major) to Rout.
__global__ void __launch_bounds__(DDIM) mlp_rmat_kernel(
    const float* __restrict__ persp,  // [NB, FDIM]
    const float* __restrict__ W1,     // [FDIM, DDIM]
    const float* __restrict__ b1,     // [DDIM]
    const float* __restrict__ W2,     // [DDIM, DDIM]
    const float* __restrict__ b2,     // [DDIM]
    const float* __restrict__ Wp,     // [DDIM, 3]
    const float* __restrict__ bp,     // [3]
    float* __restrict__ Rout)         // [NB, 9]
{
    const int n = blockIdx.x;
    const int d = threadIdx.x;

    __shared__ float sh1[DDIM];
    __shared__ float sh2[DDIM];
    __shared__ float ang[3];

    // layer 1: h1 = gelu(p @ W1 + b1) * gamma
    float acc = b1[d];
#pragma unroll
    for (int f = 0; f < FDIM; ++f)
        acc += persp[n * FDIM + f] * W1[f * DDIM + d];
    sh1[d] = gelu_gamma(acc);
    __syncthreads();

    // layer 2: h2 = gelu(h1 @ W2 + b2) * gamma
    float acc2 = b2[d];
#pragma unroll 8
    for (int k = 0; k < DDIM; ++k)
        acc2 += sh1[k] * W2[k * DDIM + d];
    sh2[d] = gelu_gamma(acc2);
    __syncthreads();

    // head: ang = h2 @ Wp + bp   (3 threads, 128 MACs each — trivial)
    if (d < 3) {
        float a = bp[d];
#pragma unroll 8
        for (int k = 0; k < DDIM; ++k)
            a += sh2[k] * Wp[k * 3 + d];
        ang[d] = a;
    }
    __syncthreads();

    // R = Rz @ Ry @ Rx
    if (d == 0) {
        float cx = cosf(ang[0]), sx = sinf(ang[0]);
        float cy = cosf(ang[1]), sy = sinf(ang[1]);
        float cz = cosf(ang[2]), sz = sinf(ang[2]);
        float* R = Rout + n * 9;
        R[0] = cz * cy;  R[1] = cz * sy * sx - sz * cx;  R[2] = cz * sy * cx + sz * sx;
        R[3] = sz * cy;  R[4] = sz * sy * sx + cz * cx;  R[5] = sz * sy * cx - cz * sx;
        R[6] = -sy;      R[7] = cy * sx;                 R[8] = cy * cx;
    }
}

__device__ __forceinline__ float fetch_px(const float* __restrict__ img, int yi, int xi) {
    bool valid = (xi >= 0) & (xi < IMG_W) & (yi >= 0) & (yi < IMG_H);
    return valid ? img[yi * IMG_W + xi] : 0.0f;
}

// grid = (HR, NB), block = WR. One thread per output pixel.
__global__ void __launch_bounds__(WR) retina_sample_kernel(
    const float* __restrict__ stim,   // [NB, 1, IMG_H, IMG_W]
    const float* __restrict__ Rmat,   // [NB, 9]
    float* __restrict__ out)          // [NB, 1, HR, WR]
{
    const int w = threadIdx.x;
    const int h = blockIdx.x;
    const int n = blockIdx.y;

    // Block-uniform rotation matrix (uniform address -> scalar loads)
    const float* Rn = Rmat + n * 9;
    const float r0 = Rn[0], r1 = Rn[1], r2 = Rn[2];
    const float r3 = Rn[3], r4 = Rn[4], r5 = Rn[5];
    const float r6 = Rn[6], r7 = Rn[7], r8 = Rn[8];

    // isotropic pixel-center coords (m = max(HR,WR) = 256)
    const float gx = (2.0f * w + 1.0f - 256.0f) * (1.0f / 256.0f);
    const float gy = (2.0f * h + 1.0f - 144.0f) * (1.0f / 256.0f);

    // angular retina direction
    const float axv = gx * FOV_HALF_RAD;
    const float ayv = gy * FOV_HALF_RAD;
    const float a   = sqrtf(axv * axv + ayv * ayv) + 1e-12f;
    const float sc  = sinf(a) / a;
    const float dx = sc * axv, dy = sc * ayv, dz = cosf(a);

    // rotate
    const float rx = r0 * dx + r1 * dy + r2 * dz;
    const float ry = r3 * dx + r4 * dy + r5 * dz;
    const float rz = r6 * dx + r7 * dy + r8 * dz;

    // monitor projection
    float gxp, gyp;
    if (rz > 0.001f) {
        gxp = rx / rz;
        gyp = ry / rz;
    } else {
        gxp = OUT_OF_RANGE;
        gyp = OUT_OF_RANGE;
    }

    // isotropic grid -> pixel coords (m = max(IMG_H,IMG_W) = 256)
    const float px = (gxp * 256.0f + (float)(IMG_W - 1)) * 0.5f;
    const float py = (gyp * 256.0f + (float)(IMG_H - 1)) * 0.5f;

    const float x0f = floorf(px), y0f = floorf(py);
    const float wx = px - x0f, wy = py - y0f;
    const int x0 = (int)x0f, y0 = (int)y0f;

    const float* __restrict__ img = stim + (size_t)n * (IMG_H * IMG_W);
    const float v00 = fetch_px(img, y0,     x0);
    const float v01 = fetch_px(img, y0,     x0 + 1);
    const float v10 = fetch_px(img, y0 + 1, x0);
    const float v11 = fetch_px(img, y0 + 1, x0 + 1);

    const float top = v00 * (1.0f - wx) + v01 * wx;
    const float bot = v10 * (1.0f - wx) + v11 * wx;
    const float val = top * (1.0f - wy) + bot * wy;

    out[((size_t)n * HR + h) * WR + w] = val;
}

extern "C" void kernel_launch(void* const* d_in, const int* in_sizes, int n_in,
                              void* d_out, int out_size, void* d_ws, size_t ws_size,
                              hipStream_t stream) {
    const float* stimulus    = (const float*)d_in[0]; // [256,1,144,256]
    const float* perspective = (const float*)d_in[1]; // [256,16]
    const float* W1          = (const float*)d_in[2]; // [16,128]
    const float* b1          = (const float*)d_in[3]; // [128]
    const float* W2          = (const float*)d_in[4]; // [128,128]
    const float* b2          = (const float*)d_in[5]; // [128]
    const float* Wp          = (const float*)d_in[6]; // [128,3]
    const float* bp          = (const float*)d_in[7]; // [3]
    float* out = (float*)d_out;

    float* Rmat = (float*)d_ws; // 256*9 floats = 9216 B

    mlp_rmat_kernel<<<NB, DDIM, 0, stream>>>(
        perspective, W1, b1, W2, b2, Wp, bp, Rmat);

    dim3 grid(HR, NB);
    retina_sample_kernel<<<grid, WR, 0, stream>>>(stimulus, Rmat, out);
}

// Round 2
// 126.813 us; speedup vs baseline: 1.0383x; 1.0383x over previous
//
#include <hip/hip_runtime.h>
#include <math.h>

// Problem constants (reference: N=256, S=1, stimulus 144x256, retina 144x256)
#define NB    256
#define IMG_H 144
#define IMG_W 256
#define HR    144
#define WR    256
#define FDIM  16
#define DDIM  128

#define FOV_HALF_RAD 0.6544984694978736f   // 0.5 * 75deg in rad
#define GELU_GAMMA   1.7015043497085571f
#define OUT_OF_RANGE 10.0f

// jax.nn.gelu default is approximate=True (tanh form)
__device__ __forceinline__ float gelu_gamma(float x) {
    const float k0 = 0.7978845608028654f;  // sqrt(2/pi)
    const float k1 = 0.044715f;
    float t = tanhf(k0 * (x + k1 * x * x * x));
    return 0.5f * x * (1.0f + t) * GELU_GAMMA;
}

// One block per batch element; 128 threads = hidden dim.
// Writes R[n] (9 floats, row-major) to Rout. Cost negligible (~few us total).
__global__ void __launch_bounds__(DDIM) mlp_rmat_kernel(
    const float* __restrict__ persp,  // [NB, FDIM]
    const float* __restrict__ W1,     // [FDIM, DDIM]
    const float* __restrict__ b1,     // [DDIM]
    const float* __restrict__ W2,     // [DDIM, DDIM]
    const float* __restrict__ b2,     // [DDIM]
    const float* __restrict__ Wp,     // [DDIM, 3]
    const float* __restrict__ bp,     // [3]
    float* __restrict__ Rout)         // [NB, 9]
{
    const int n = blockIdx.x;
    const int d = threadIdx.x;

    __shared__ float sh1[DDIM];
    __shared__ float sh2[DDIM];
    __shared__ float ang[3];

    // layer 1: h1 = gelu(p @ W1 + b1) * gamma
    float acc = b1[d];
#pragma unroll
    for (int f = 0; f < FDIM; ++f)
        acc += persp[n * FDIM + f] * W1[f * DDIM + d];
    sh1[d] = gelu_gamma(acc);
    __syncthreads();

    // layer 2: h2 = gelu(h1 @ W2 + b2) * gamma
    float acc2 = b2[d];
#pragma unroll 8
    for (int k = 0; k < DDIM; ++k)
        acc2 += sh1[k] * W2[k * DDIM + d];
    sh2[d] = gelu_gamma(acc2);
    __syncthreads();

    // head: ang = h2 @ Wp + bp
    if (d < 3) {
        float a = bp[d];
#pragma unroll 8
        for (int k = 0; k < DDIM; ++k)
            a += sh2[k] * Wp[k * 3 + d];
        ang[d] = a;
    }
    __syncthreads();

    // R = Rz @ Ry @ Rx  (per-batch, 1 thread — trivial)
    if (d == 0) {
        float cx = cosf(ang[0]), sx = sinf(ang[0]);
        float cy = cosf(ang[1]), sy = sinf(ang[1]);
        float cz = cosf(ang[2]), sz = sinf(ang[2]);
        float* R = Rout + n * 9;
        R[0] = cz * cy;  R[1] = cz * sy * sx - sz * cx;  R[2] = cz * sy * cx + sz * sx;
        R[3] = sz * cy;  R[4] = sz * sy * sx + cz * cx;  R[5] = sz * sy * cx - cz * sx;
        R[6] = -sy;      R[7] = cy * sx;                 R[8] = cy * cx;
    }
}

__device__ __forceinline__ float fetch_px(const float* __restrict__ img, int yi, int xi) {
    bool valid = (xi >= 0) & (xi < IMG_W) & (yi >= 0) & (yi < IMG_H);
    return valid ? img[yi * IMG_W + xi] : 0.0f;
}

// grid = (HR, NB), block = WR. One thread per output pixel.
// VALU-lean version: sinc(a) and cos(a) are even functions of a, so evaluate
// them as Taylor polynomials in t = ax^2+ay^2 (t <= 0.56 for this FOV):
// truncation error ~1e-8 — no sqrt/sin/cos/divide in the hot path at all.
__global__ void __launch_bounds__(WR) retina_sample_kernel(
    const float* __restrict__ stim,   // [NB, 1, IMG_H, IMG_W]
    const float* __restrict__ Rmat,   // [NB, 9]
    float* __restrict__ out)          // [NB, 1, HR, WR]
{
    const int w = threadIdx.x;
    const int h = blockIdx.x;
    const int n = blockIdx.y;

    // Block-uniform rotation matrix (uniform address -> scalar loads)
    const float* Rn = Rmat + n * 9;
    const float r0 = Rn[0], r1 = Rn[1], r2 = Rn[2];
    const float r3 = Rn[3], r4 = Rn[4], r5 = Rn[5];
    const float r6 = Rn[6], r7 = Rn[7], r8 = Rn[8];

    // isotropic pixel-center coords (m = max(HR,WR) = 256)
    const float gx = (2.0f * w + 1.0f - 256.0f) * (1.0f / 256.0f);
    const float gy = (2.0f * h + 1.0f - 144.0f) * (1.0f / 256.0f);

    const float axv = gx * FOV_HALF_RAD;
    const float ayv = gy * FOV_HALF_RAD;
    const float t   = axv * axv + ayv * ayv;      // t = a^2, t <= 0.56

    // sinc(a) = 1 - t/6 + t^2/120 - t^3/5040 + t^4/362880   (Horner)
    float sc = fmaf(t, 2.7557319e-6f, -1.9841270e-4f);
    sc = fmaf(t, sc,  8.3333333e-3f);
    sc = fmaf(t, sc, -1.6666667e-1f);
    sc = fmaf(t, sc,  1.0f);

    // cos(a) = 1 - t/2 + t^2/24 - t^3/720 + t^4/40320
    float ca = fmaf(t, 2.4801587e-5f, -1.3888889e-3f);
    ca = fmaf(t, ca,  4.1666667e-2f);
    ca = fmaf(t, ca, -0.5f);
    ca = fmaf(t, ca,  1.0f);

    const float dx = sc * axv, dy = sc * ayv, dz = ca;

    // rotate
    const float rx = r0 * dx + r1 * dy + r2 * dz;
    const float ry = r3 * dx + r4 * dy + r5 * dz;
    const float rz = r6 * dx + r7 * dy + r8 * dz;

    // monitor projection: fast reciprocal (v_rcp_f32, ~1 ulp).
    // Bilinear w/ zero-pad is continuous in (px,py), and rays near the
    // rz<=0.001 guard map far out-of-range on both sides -> 1ulp-safe.
    const float inv = __builtin_amdgcn_rcpf(rz);
    const bool safe = rz > 0.001f;
    const float gxp = safe ? rx * inv : OUT_OF_RANGE;
    const float gyp = safe ? ry * inv : OUT_OF_RANGE;

    // isotropic grid -> pixel coords (m = max(IMG_H,IMG_W) = 256)
    const float px = fmaf(gxp, 256.0f, (float)(IMG_W - 1)) * 0.5f;
    const float py = fmaf(gyp, 256.0f, (float)(IMG_H - 1)) * 0.5f;

    const float x0f = floorf(px), y0f = floorf(py);
    const float wx = px - x0f, wy = py - y0f;
    const int x0 = (int)x0f, y0 = (int)y0f;

    const float* __restrict__ img = stim + (size_t)n * (IMG_H * IMG_W);
    const float v00 = fetch_px(img, y0,     x0);
    const float v01 = fetch_px(img, y0,     x0 + 1);
    const float v10 = fetch_px(img, y0 + 1, x0);
    const float v11 = fetch_px(img, y0 + 1, x0 + 1);

    const float top = v00 * (1.0f - wx) + v01 * wx;
    const float bot = v10 * (1.0f - wx) + v11 * wx;
    const float val = top * (1.0f - wy) + bot * wy;

    out[((size_t)n * HR + h) * WR + w] = val;
}

extern "C" void kernel_launch(void* const* d_in, const int* in_sizes, int n_in,
                              void* d_out, int out_size, void* d_ws, size_t ws_size,
                              hipStream_t stream) {
    const float* stimulus    = (const float*)d_in[0]; // [256,1,144,256]
    const float* perspective = (const float*)d_in[1]; // [256,16]
    const float* W1          = (const float*)d_in[2]; // [16,128]
    const float* b1          = (const float*)d_in[3]; // [128]
    const float* W2          = (const float*)d_in[4]; // [128,128]
    const float* b2          = (const float*)d_in[5]; // [128]
    const float* Wp          = (const float*)d_in[6]; // [128,3]
    const float* bp          = (const float*)d_in[7]; // [3]
    float* out = (float*)d_out;

    float* Rmat = (float*)d_ws; // 256*9 floats = 9216 B

    mlp_rmat_kernel<<<NB, DDIM, 0, stream>>>(
        perspective, W1, b1, W2, b2, Wp, bp, Rmat);

    dim3 grid(HR, NB);
    retina_sample_kernel<<<grid, WR, 0, stream>>>(stimulus, Rmat, out);
}